// Round 1
// baseline (666.119 us; speedup 1.0000x reference)
//
#include <hip/hip_runtime.h>
#include <math.h>

#define NB   32
#define CC   512
#define DD   2048
#define HWP  196
#define NHW  6272
#define HID  256
#define TJ   64
#define TJ1  16

// ---------- kernel 1a: h_glb = gf @ W1[:D] + b1   (32 x 256) ----------
__global__ __launch_bounds__(1024) void hglb_kernel(const float* __restrict__ gf,
                                                    const float* __restrict__ W1,
                                                    const float* __restrict__ b1,
                                                    float* __restrict__ h_glb) {
    __shared__ float sP[4][HID];
    int i   = blockIdx.x;
    int tid = threadIdx.x;
    int k   = tid & (HID - 1);
    int rc  = tid >> 8;                 // 0..3
    const float* g = gf + (size_t)i * DD;
    int r0 = rc * (DD / 4);
    float acc = 0.f;
    #pragma unroll 4
    for (int r = 0; r < DD / 4; r++) {
        acc = fmaf(g[r0 + r], W1[(size_t)(r0 + r) * HID + k], acc);
    }
    sP[rc][k] = acc;
    __syncthreads();
    if (tid < HID) {
        h_glb[(size_t)i * HID + tid] = b1[tid] + sP[0][tid] + sP[1][tid] + sP[2][tid] + sP[3][tid];
    }
}

// ---------- kernel 1b: h_loc = lf_perm @ W1[D:]   (6272 x 256) ----------
// lf_perm[j][c] = local_feature[n][c][h][w],  j = n*196 + h*14 + w
__global__ __launch_bounds__(256) void hloc_kernel(const float* __restrict__ lf,
                                                   const float* __restrict__ W1c, // pre-offset to row D
                                                   float* __restrict__ h_loc) {
    __shared__ float sLf[TJ1][CC + 4];   // +4 pad: 2-way max bank alias, 16B-aligned rows
    int j0  = blockIdx.x * TJ1;
    int tid = threadIdx.x;
    {   // stage: lanes 0..15 cover consecutive j (coalesced p), groups cover c
        int row = tid & 15;
        int cb  = tid >> 4;              // 0..15
        int j = j0 + row;
        int n = j / HWP;
        int p = j - n * HWP;
        const float* base = lf + (size_t)n * CC * HWP + p;
        for (int c = cb; c < CC; c += 16) {
            sLf[row][c] = base[(size_t)c * HWP];
        }
    }
    __syncthreads();
    int kx = tid & 63, jy = tid >> 6;
    int kb = kx * 4, jb = jy * 4;
    float acc[4][4] = {};
    #pragma unroll 2
    for (int m = 0; m < CC; m += 4) {
        float4 b0 = *(const float4*)&W1c[(size_t)(m + 0) * HID + kb];
        float4 b1v = *(const float4*)&W1c[(size_t)(m + 1) * HID + kb];
        float4 b2v = *(const float4*)&W1c[(size_t)(m + 2) * HID + kb];
        float4 b3v = *(const float4*)&W1c[(size_t)(m + 3) * HID + kb];
        #pragma unroll
        for (int r = 0; r < 4; r++) {
            float4 a = *(const float4*)&sLf[jb + r][m];   // wave-broadcast read
            acc[r][0] += a.x * b0.x + a.y * b1v.x + a.z * b2v.x + a.w * b3v.x;
            acc[r][1] += a.x * b0.y + a.y * b1v.y + a.z * b2v.y + a.w * b3v.y;
            acc[r][2] += a.x * b0.z + a.y * b1v.z + a.z * b2v.z + a.w * b3v.z;
            acc[r][3] += a.x * b0.w + a.y * b1v.w + a.z * b2v.w + a.w * b3v.w;
        }
    }
    for (int r = 0; r < 4; r++) {
        float4 o = make_float4(acc[r][0], acc[r][1], acc[r][2], acc[r][3]);
        *(float4*)&h_loc[(size_t)(j0 + jb + r) * HID + kb] = o;
    }
}

// ---------- kernel 2: fused scores[i][j] = relu(relu(h_glb[i]+h_loc[j])@W2 + b2) . W3 + b3 ----------
__global__ __launch_bounds__(256, 2) void score_kernel(const float* __restrict__ h_loc,
                                                       const float* __restrict__ h_glb,
                                                       const float* __restrict__ W2,
                                                       const float* __restrict__ b2,
                                                       const float* __restrict__ W3,
                                                       const float* __restrict__ b3,
                                                       float* __restrict__ scores) {
    __shared__ float sA[TJ][HID];        // h1 tile, 64 KB
    __shared__ float sG[HID];
    int i   = blockIdx.y;
    int j0  = blockIdx.x * TJ;
    int tid = threadIdx.x;
    sG[tid] = h_glb[(size_t)i * HID + tid];
    __syncthreads();
    // build h1 = relu(h_loc + h_glb) in LDS (coalesced float4 loads)
    for (int x = tid; x < TJ * HID / 4; x += 256) {
        int row = x >> 6;                // / (HID/4)
        int m4  = (x & 63) << 2;
        float4 v = *(const float4*)&h_loc[(size_t)(j0 + row) * HID + m4];
        v.x = fmaxf(v.x + sG[m4 + 0], 0.f);
        v.y = fmaxf(v.y + sG[m4 + 1], 0.f);
        v.z = fmaxf(v.z + sG[m4 + 2], 0.f);
        v.w = fmaxf(v.w + sG[m4 + 3], 0.f);
        *(float4*)&sA[row][m4] = v;
    }
    __syncthreads();
    // register tile: wave jy handles rows jb..jb+15, lane kx handles cols kb..kb+3
    int kx = tid & 63, jy = tid >> 6;
    int kb = kx * 4, jb = jy * 16;
    float acc[16][4] = {};
    #pragma unroll 2
    for (int m = 0; m < HID; m += 4) {
        float4 b0 = *(const float4*)&W2[(size_t)(m + 0) * HID + kb];
        float4 b1v = *(const float4*)&W2[(size_t)(m + 1) * HID + kb];
        float4 b2v = *(const float4*)&W2[(size_t)(m + 2) * HID + kb];
        float4 b3v = *(const float4*)&W2[(size_t)(m + 3) * HID + kb];
        #pragma unroll
        for (int r = 0; r < 16; r++) {
            float4 a = *(const float4*)&sA[jb + r][m];   // wave-broadcast read
            acc[r][0] += a.x * b0.x + a.y * b1v.x + a.z * b2v.x + a.w * b3v.x;
            acc[r][1] += a.x * b0.y + a.y * b1v.y + a.z * b2v.y + a.w * b3v.y;
            acc[r][2] += a.x * b0.z + a.y * b1v.z + a.z * b2v.z + a.w * b3v.z;
            acc[r][3] += a.x * b0.w + a.y * b1v.w + a.z * b2v.w + a.w * b3v.w;
        }
    }
    // epilogue: relu(+b2), dot W3, wave-reduce over the 64 lanes (k), lane0 writes
    float4 w3v = *(const float4*)&W3[kb];
    float4 bbv = *(const float4*)&b2[kb];
    float bias3 = b3[0];
    #pragma unroll
    for (int r = 0; r < 16; r++) {
        float s = fmaxf(acc[r][0] + bbv.x, 0.f) * w3v.x
                + fmaxf(acc[r][1] + bbv.y, 0.f) * w3v.y
                + fmaxf(acc[r][2] + bbv.z, 0.f) * w3v.z
                + fmaxf(acc[r][3] + bbv.w, 0.f) * w3v.w;
        #pragma unroll
        for (int off = 32; off > 0; off >>= 1) s += __shfl_down(s, off, 64);
        if (kx == 0) scores[(size_t)i * NHW + j0 + jb + r] = s + bias3;
    }
}

// ---------- kernel 3: per-row max, masked log-mean-exp, write mi ----------
__global__ __launch_bounds__(256) void reduce_kernel(const float* __restrict__ scores,
                                                     float* __restrict__ out) {
    int i   = blockIdx.x;
    int tid = threadIdx.x;
    const float* row = scores + (size_t)i * NHW;
    __shared__ float sA_[4], sB_[4], sval[2];
    // phase 1: max over all j
    float mx = -1e30f;
    for (int j = tid; j < NHW; j += 256) mx = fmaxf(mx, row[j]);
    #pragma unroll
    for (int off = 32; off > 0; off >>= 1) mx = fmaxf(mx, __shfl_down(mx, off, 64));
    if ((tid & 63) == 0) sA_[tid >> 6] = mx;
    __syncthreads();
    if (tid == 0) sval[0] = fmaxf(fmaxf(sA_[0], sA_[1]), fmaxf(sA_[2], sA_[3]));
    __syncthreads();
    mx = sval[0];
    // phase 2: total and own sums of exp(s - mx)
    int own0 = i * HWP, own1 = own0 + HWP;
    float tot = 0.f, ownv = 0.f;
    for (int j = tid; j < NHW; j += 256) {
        float e = expf(row[j] - mx);
        tot += e;
        if (j >= own0 && j < own1) ownv += e;
    }
    #pragma unroll
    for (int off = 32; off > 0; off >>= 1) {
        tot  += __shfl_down(tot, off, 64);
        ownv += __shfl_down(ownv, off, 64);
    }
    if ((tid & 63) == 0) { sA_[tid >> 6] = tot; sB_[tid >> 6] = ownv; }
    __syncthreads();
    if (tid == 0) {
        float t = sA_[0] + sA_[1] + sA_[2] + sA_[3];
        float o = sB_[0] + sB_[1] + sB_[2] + sB_[3];
        float neg_mean = (t - o) / (float)(NHW - HWP) + 1e-10f;
        sval[1] = mx + logf(neg_mean);
    }
    __syncthreads();
    float sub = sval[1];
    if (tid < HWP) out[(size_t)i * HWP + tid] = row[own0 + tid] - sub;
}

extern "C" void kernel_launch(void* const* d_in, const int* in_sizes, int n_in,
                              void* d_out, int out_size, void* d_ws, size_t ws_size,
                              hipStream_t stream) {
    const float* lf = (const float*)d_in[0];   // (32,512,14,14)
    const float* gf = (const float*)d_in[1];   // (32,2048,1,1)
    const float* W1 = (const float*)d_in[2];   // (2560,256)
    const float* b1 = (const float*)d_in[3];   // (256)
    const float* W2 = (const float*)d_in[4];   // (256,256)
    const float* b2 = (const float*)d_in[5];   // (256)
    const float* W3 = (const float*)d_in[6];   // (256,1)
    const float* b3 = (const float*)d_in[7];   // (1)
    float* out = (float*)d_out;

    float* ws     = (float*)d_ws;
    float* h_loc  = ws;                          // 6272*256
    float* h_glb  = h_loc + (size_t)NHW * HID;   // 32*256
    float* scores = h_glb + (size_t)NB * HID;    // 32*6272

    hipLaunchKernelGGL(hglb_kernel, dim3(NB), dim3(1024), 0, stream, gf, W1, b1, h_glb);
    hipLaunchKernelGGL(hloc_kernel, dim3(NHW / TJ1), dim3(256), 0, stream,
                       lf, W1 + (size_t)DD * HID, h_loc);
    hipLaunchKernelGGL(score_kernel, dim3(NHW / TJ, NB), dim3(256), 0, stream,
                       h_loc, h_glb, W2, b2, W3, b3, scores);
    hipLaunchKernelGGL(reduce_kernel, dim3(NB), dim3(256), 0, stream, scores, out);
}

// Round 2
// 238.242 us; speedup vs baseline: 2.7960x; 2.7960x over previous
//
#include <hip/hip_runtime.h>
#include <math.h>

#define NB   32
#define CC   512
#define DD   2048
#define HWP  196
#define NHW  6272
#define HID  256
#define TJ1  16

typedef _Float16 h8 __attribute__((ext_vector_type(8)));
typedef _Float16 h4 __attribute__((ext_vector_type(4)));
typedef float    f4 __attribute__((ext_vector_type(4)));

union F4H8 { f4 f; h8 h; };

// ---------- kernel 1a: h_glb = gf @ W1[:D] + b1   (32 x 256, fp32) ----------
__global__ __launch_bounds__(1024) void hglb_kernel(const float* __restrict__ gf,
                                                    const float* __restrict__ W1,
                                                    const float* __restrict__ b1,
                                                    float* __restrict__ h_glb) {
    __shared__ float sP[4][HID];
    int i   = blockIdx.x;
    int tid = threadIdx.x;
    int k   = tid & (HID - 1);
    int rc  = tid >> 8;
    const float* g = gf + (size_t)i * DD;
    int r0 = rc * (DD / 4);
    float acc = 0.f;
    #pragma unroll 4
    for (int r = 0; r < DD / 4; r++)
        acc = fmaf(g[r0 + r], W1[(size_t)(r0 + r) * HID + k], acc);
    sP[rc][k] = acc;
    __syncthreads();
    if (tid < HID)
        h_glb[(size_t)i * HID + tid] = b1[tid] + sP[0][tid] + sP[1][tid] + sP[2][tid] + sP[3][tid];
}

// ---------- kernel 1b: h_loc = lf_perm @ W1[D:]  (6272 x 256, fp32 math, fp16 store) ----------
__global__ __launch_bounds__(256) void hloc_kernel(const float* __restrict__ lf,
                                                   const float* __restrict__ W1c,
                                                   _Float16* __restrict__ h_loc) {
    __shared__ float sLf[TJ1][CC + 4];
    int j0  = blockIdx.x * TJ1;
    int tid = threadIdx.x;
    {
        int row = tid & 15;
        int cb  = tid >> 4;
        int j = j0 + row;
        int n = j / HWP;
        int p = j - n * HWP;
        const float* base = lf + (size_t)n * CC * HWP + p;
        for (int c = cb; c < CC; c += 16) sLf[row][c] = base[(size_t)c * HWP];
    }
    __syncthreads();
    int kx = tid & 63, jy = tid >> 6;
    int kb = kx * 4, jb = jy * 4;
    float acc[4][4] = {};
    #pragma unroll 2
    for (int m = 0; m < CC; m += 4) {
        float4 b0 = *(const float4*)&W1c[0]; // placeholder to keep layout clear (overwritten below)
        b0          = *(const float4*)((const float*)W1c + (size_t)(m + 0) * HID + kb);
        float4 b1v  = *(const float4*)((const float*)W1c + (size_t)(m + 1) * HID + kb);
        float4 b2v  = *(const float4*)((const float*)W1c + (size_t)(m + 2) * HID + kb);
        float4 b3v  = *(const float4*)((const float*)W1c + (size_t)(m + 3) * HID + kb);
        #pragma unroll
        for (int r = 0; r < 4; r++) {
            float4 a = *(const float4*)&sLf[jb + r][m];
            acc[r][0] += a.x * b0.x + a.y * b1v.x + a.z * b2v.x + a.w * b3v.x;
            acc[r][1] += a.x * b0.y + a.y * b1v.y + a.z * b2v.y + a.w * b3v.y;
            acc[r][2] += a.x * b0.z + a.y * b1v.z + a.z * b2v.z + a.w * b3v.z;
            acc[r][3] += a.x * b0.w + a.y * b1v.w + a.z * b2v.w + a.w * b3v.w;
        }
    }
    for (int r = 0; r < 4; r++) {
        h4 o = { (_Float16)acc[r][0], (_Float16)acc[r][1], (_Float16)acc[r][2], (_Float16)acc[r][3] };
        *(h4*)&h_loc[(size_t)(j0 + jb + r) * HID + kb] = o;
    }
}
// NOTE: hloc uses W1c as const float* — fix type in launch (cast).

// ---------- prep: W2 (256x256 fp32, row-major [k][n]) -> fp16 B-fragments ----------
// frag F = nt*8 + ks (nt 0..15, ks 0..7); lane l holds B[k=ks*32+(l>>4)*8+j][n=nt*16+(l&15)], j=0..7
__global__ __launch_bounds__(256) void w2frag_kernel(const float* __restrict__ W2,
                                                     _Float16* __restrict__ out) {
    int t = blockIdx.x * 256 + threadIdx.x;      // 0..8191
    int F = t >> 6, l = t & 63;
    int nt = F >> 3, ks = F & 7;
    int kb = ks * 32 + (l >> 4) * 8;
    int n  = nt * 16 + (l & 15);
    _Float16* o = out + (size_t)t * 8;
    #pragma unroll
    for (int j = 0; j < 8; j++)
        o[j] = (_Float16)W2[(size_t)(kb + j) * HID + n];
}

// ---------- kernel 2: fused MFMA scores ----------
// persistent: 448 blocks x 2 waves; block i = bid&31 fixed; 7 tiles of 64 j-rows
__global__ __launch_bounds__(128, 1) void score_kernel(const _Float16* __restrict__ h_loc,
                                                       const float* __restrict__ h_glb,
                                                       const _Float16* __restrict__ Bfrag,
                                                       const float* __restrict__ b2,
                                                       const float* __restrict__ W3,
                                                       const float* __restrict__ b3,
                                                       float* __restrict__ scores) {
    __shared__ _Float16 sA[64 * HID];     // 32 KB, row-major [64 j][256 m]
    __shared__ float sG[HID];
    __shared__ float sRed[2][64];

    int tid  = threadIdx.x;
    int w    = tid >> 6;                  // wave 0/1
    int l    = tid & 63;
    int quad = l >> 4;
    int bid  = blockIdx.x;
    int i    = bid & 31;

    // h_glb row for this block's i
    for (int x = tid; x < HID; x += 128) sG[x] = h_glb[(size_t)i * HID + x];

    // B fragments: 64 per wave, held in registers for the whole kernel
    F4H8 Bf[64];
    {
        const f4* src = (const f4*)(Bfrag + (size_t)w * 64 * 64 * 8) + l;
        #pragma unroll
        for (int q = 0; q < 64; q++) Bf[q].f = src[q * 64];
    }
    // per-lane epilogue constants: k2 = w*128 + nt*16 + (l&15)
    float w3r[8], b2r[8];
    #pragma unroll
    for (int nt = 0; nt < 8; nt++) {
        int k2 = w * 128 + nt * 16 + (l & 15);
        w3r[nt] = W3[k2];
        b2r[nt] = b2[k2];
    }
    float bias3 = b3[0];
    __syncthreads();

    for (int it = 0; it < 7; it++) {
        int j0 = ((bid >> 5) + 14 * it) * 64;

        // stage A: h1 = relu(h_loc + h_glb) -> fp16 LDS
        #pragma unroll 4
        for (int s = 0; s < 16; s++) {
            int x   = s * 128 + tid;       // 0..2047
            int row = x >> 5;
            int g   = x & 31;
            int k0  = g * 8;
            h8 hv = *(const h8*)&h_loc[(size_t)(j0 + row) * HID + k0];
            h8 ov;
            #pragma unroll
            for (int e = 0; e < 8; e++) {
                float v = (float)hv[e] + sG[k0 + e];
                ov[e] = (_Float16)fmaxf(v, 0.f);
            }
            *(h8*)&sA[row * HID + k0] = ov;
        }
        __syncthreads();

        // MFMA: per wave M=64 (4 m-tiles) x N=128 (8 n-tiles), K=256 (8 ks)
        f4 acc[32] = {};
        #pragma unroll
        for (int ks = 0; ks < 8; ks++) {
            h8 aF[4];
            #pragma unroll
            for (int mt = 0; mt < 4; mt++)
                aF[mt] = *(const h8*)&sA[(mt * 16 + (l & 15)) * HID + ks * 32 + quad * 8];
            #pragma unroll
            for (int nt = 0; nt < 8; nt++) {
                h8 bF = Bf[nt * 8 + ks].h;
                #pragma unroll
                for (int mt = 0; mt < 4; mt++)
                    acc[mt * 8 + nt] = __builtin_amdgcn_mfma_f32_16x16x32_f16(aF[mt], bF, acc[mt * 8 + nt], 0, 0, 0);
            }
        }

        // epilogue: relu(+b2) . W3, reduce over lanes (n), cross-wave via LDS
        #pragma unroll
        for (int mt = 0; mt < 4; mt++) {
            #pragma unroll
            for (int r = 0; r < 4; r++) {
                float s = 0.f;
                #pragma unroll
                for (int nt = 0; nt < 8; nt++)
                    s += fmaxf(acc[mt * 8 + nt][r] + b2r[nt], 0.f) * w3r[nt];
                s += __shfl_xor(s, 1, 64);
                s += __shfl_xor(s, 2, 64);
                s += __shfl_xor(s, 4, 64);
                s += __shfl_xor(s, 8, 64);
                if ((l & 15) == 0) sRed[w][mt * 16 + quad * 4 + r] = s;
            }
        }
        __syncthreads();
        if (tid < 64)
            scores[(size_t)i * NHW + j0 + tid] = sRed[0][tid] + sRed[1][tid] + bias3;
        // next staging writes sA only after all threads pass the staging loop's
        // __syncthreads of iteration it+1; sRed reads above happen before that.
    }
}

// ---------- kernel 3: per-row max, masked log-mean-exp, write mi ----------
__global__ __launch_bounds__(256) void reduce_kernel(const float* __restrict__ scores,
                                                     float* __restrict__ out) {
    int i   = blockIdx.x;
    int tid = threadIdx.x;
    const float* row = scores + (size_t)i * NHW;
    __shared__ float sA_[4], sB_[4], sval[2];
    float mx = -1e30f;
    for (int j = tid; j < NHW; j += 256) mx = fmaxf(mx, row[j]);
    #pragma unroll
    for (int off = 32; off > 0; off >>= 1) mx = fmaxf(mx, __shfl_down(mx, off, 64));
    if ((tid & 63) == 0) sA_[tid >> 6] = mx;
    __syncthreads();
    if (tid == 0) sval[0] = fmaxf(fmaxf(sA_[0], sA_[1]), fmaxf(sA_[2], sA_[3]));
    __syncthreads();
    mx = sval[0];
    int own0 = i * HWP, own1 = own0 + HWP;
    float tot = 0.f, ownv = 0.f;
    for (int j = tid; j < NHW; j += 256) {
        float e = expf(row[j] - mx);
        tot += e;
        if (j >= own0 && j < own1) ownv += e;
    }
    #pragma unroll
    for (int off = 32; off > 0; off >>= 1) {
        tot  += __shfl_down(tot, off, 64);
        ownv += __shfl_down(ownv, off, 64);
    }
    if ((tid & 63) == 0) { sA_[tid >> 6] = tot; sB_[tid >> 6] = ownv; }
    __syncthreads();
    if (tid == 0) {
        float t = sA_[0] + sA_[1] + sA_[2] + sA_[3];
        float o = sB_[0] + sB_[1] + sB_[2] + sB_[3];
        float neg_mean = (t - o) / (float)(NHW - HWP) + 1e-10f;
        sval[1] = mx + logf(neg_mean);
    }
    __syncthreads();
    float sub = sval[1];
    if (tid < HWP) out[(size_t)i * HWP + tid] = row[own0 + tid] - sub;
}

extern "C" void kernel_launch(void* const* d_in, const int* in_sizes, int n_in,
                              void* d_out, int out_size, void* d_ws, size_t ws_size,
                              hipStream_t stream) {
    const float* lf = (const float*)d_in[0];
    const float* gf = (const float*)d_in[1];
    const float* W1 = (const float*)d_in[2];
    const float* b1 = (const float*)d_in[3];
    const float* W2 = (const float*)d_in[4];
    const float* b2 = (const float*)d_in[5];
    const float* W3 = (const float*)d_in[6];
    const float* b3 = (const float*)d_in[7];
    float* out = (float*)d_out;

    char* ws = (char*)d_ws;
    _Float16* h_loc16 = (_Float16*)ws;                                   // 6272*256*2 = 3.21 MB
    float*    h_glb   = (float*)(ws + (size_t)NHW * HID * 2);            // 32 KB
    float*    scores  = (float*)((char*)h_glb + (size_t)NB * HID * 4);   // 802 KB
    _Float16* Bfrag   = (_Float16*)((char*)scores + (size_t)NB * NHW * 4); // 128 KB

    hipLaunchKernelGGL(hglb_kernel, dim3(NB), dim3(1024), 0, stream, gf, W1, b1, h_glb);
    hipLaunchKernelGGL(hloc_kernel, dim3(NHW / TJ1), dim3(256), 0, stream,
                       lf, W1 + (size_t)DD * HID, h_loc16);
    hipLaunchKernelGGL(w2frag_kernel, dim3(32), dim3(256), 0, stream, W2, Bfrag);
    hipLaunchKernelGGL(score_kernel, dim3(448), dim3(128), 0, stream,
                       h_loc16, h_glb, Bfrag, b2, W3, b3, scores);
    hipLaunchKernelGGL(reduce_kernel, dim3(NB), dim3(256), 0, stream, scores, out);
}

// Round 3
// 207.330 us; speedup vs baseline: 3.2128x; 1.1491x over previous
//
#include <hip/hip_runtime.h>
#include <math.h>

#define NB   32
#define CC   512
#define DD   2048
#define HWP  196
#define NHW  6272
#define HID  256

typedef _Float16 h8 __attribute__((ext_vector_type(8)));
typedef _Float16 h4 __attribute__((ext_vector_type(4)));
typedef float    f4 __attribute__((ext_vector_type(4)));
union F4H8 { f4 f; h8 h; };

// fp16 index into fragment-layout tensor for (row j, col k), K=256, 64-row j-tiles.
// Block (ks*4+nt) of 512 fp16; lane l = quad*16 + (j&15); element = k&7.
__device__ __forceinline__ int fragIdx(int j, int k) {
    return ((j >> 6) << 14) + (((k >> 5) * 4 + ((j & 63) >> 4)) << 9)
         + (((((k >> 3) & 3) << 4) + (j & 15)) << 3) + (k & 7);
}

// ---------- hglb1: partial[i][ky][k] = sum over 128 rows of gf*W1 ----------
__global__ __launch_bounds__(256) void hglb1_kernel(const float* __restrict__ gf,
                                                    const float* __restrict__ W1,
                                                    float* __restrict__ part) {
    int i = blockIdx.x, ky = blockIdx.y, k = threadIdx.x;
    const float* g = gf + (size_t)i * DD + ky * 128;
    const float* w = W1 + (size_t)(ky * 128) * HID + k;
    float acc = 0.f;
    #pragma unroll 8
    for (int r = 0; r < 128; r++) acc = fmaf(g[r], w[(size_t)r * HID], acc);
    part[((size_t)i * 16 + ky) * HID + k] = acc;
}

// ---------- hglb2: g16[i][k] = fp16(b1[k] + sum_ky part) ----------
__global__ __launch_bounds__(256) void hglb2_kernel(const float* __restrict__ part,
                                                    const float* __restrict__ b1,
                                                    _Float16* __restrict__ g16) {
    int i = blockIdx.x, k = threadIdx.x;
    float s = b1[k];
    #pragma unroll
    for (int ky = 0; ky < 16; ky++) s += part[((size_t)i * 16 + ky) * HID + k];
    g16[(size_t)i * HID + k] = (_Float16)s;
}

// ---------- w2frag: W2[256][256] fp32 -> A-operand frags (F = k2t*8 + ks) ----------
__global__ __launch_bounds__(256) void w2frag_kernel(const float* __restrict__ W2,
                                                     _Float16* __restrict__ out) {
    int t = blockIdx.x * 256 + threadIdx.x;      // 0..8191
    int F = t >> 6, l = t & 63;
    int k2t = F >> 3, ks = F & 7;
    int kb = ks * 32 + (l >> 4) * 8;
    int n  = k2t * 16 + (l & 15);
    _Float16* o = out + (size_t)t * 8;
    #pragma unroll
    for (int j = 0; j < 8; j++) o[j] = (_Float16)W2[(size_t)(kb + j) * HID + n];
}

// ---------- w1frag: W1c[512][256] fp32 -> A-operand frags (F = k2t*16 + ks) ----------
__global__ __launch_bounds__(256) void w1frag_kernel(const float* __restrict__ W1c,
                                                     _Float16* __restrict__ out) {
    int t = blockIdx.x * 256 + threadIdx.x;      // 0..16383
    int F = t >> 6, l = t & 63;
    int k2t = F >> 4, ks = F & 15;
    int kb = ks * 32 + (l >> 4) * 8;
    int n  = k2t * 16 + (l & 15);
    _Float16* o = out + (size_t)t * 8;
    #pragma unroll
    for (int j = 0; j < 8; j++) o[j] = (_Float16)W1c[(size_t)(kb + j) * HID + n];
}

// ---------- hlocF: h_loc = lf_perm @ W1[D:], MFMA, output in frag layout ----------
// grid (196 j-tiles of 32, 2 k2-halves), 256 threads = 4 waves (k2-slice 32 each)
__global__ __launch_bounds__(256, 2) void hlocF_kernel(const float* __restrict__ lf,
                                                       const _Float16* __restrict__ W1F,
                                                       _Float16* __restrict__ hF) {
    __shared__ _Float16 sLf[32 * 528];           // 32 rows x 512 (+16 pad)
    int tid = threadIdx.x;
    int w = tid >> 6, l = tid & 63, quad = l >> 4, ln = l & 15;
    int j0 = blockIdx.x * 32;
    int khalf = blockIdx.y;

    // stage: thread (jl = tid&31, ch = tid>>5) loads 64 consecutive c, strided in lf
    {
        int jl = tid & 31, ch = tid >> 5;
        int j = j0 + jl;
        int n = j / HWP;
        int p = j - n * HWP;
        const float* base = lf + (size_t)n * CC * HWP + p + (size_t)(ch * 64) * HWP;
        _Float16* dst = sLf + jl * 528 + ch * 64;
        #pragma unroll
        for (int g = 0; g < 8; g++) {
            h8 v;
            #pragma unroll
            for (int e = 0; e < 8; e++) v[e] = (_Float16)base[(size_t)(g * 8 + e) * HWP];
            *(h8*)(dst + g * 8) = v;
        }
    }

    // W1 A-frags for this wave's k2-slice (32 wide): k2t = khalf*8 + w*2 + mt
    F4H8 Af[32];
    {
        const f4* src = (const f4*)W1F + l;
        #pragma unroll
        for (int mt = 0; mt < 2; mt++)
            #pragma unroll
            for (int ks = 0; ks < 16; ks++)
                Af[mt * 16 + ks].f = src[(size_t)((khalf * 8 + w * 2 + mt) * 16 + ks) * 64];
    }
    __syncthreads();

    f4 acc[4] = {};
    #pragma unroll
    for (int ks = 0; ks < 16; ks++) {
        h8 bF[2];
        #pragma unroll
        for (int nt = 0; nt < 2; nt++)
            bF[nt] = *(const h8*)(sLf + (nt * 16 + ln) * 528 + ks * 32 + quad * 8);
        #pragma unroll
        for (int mt = 0; mt < 2; mt++)
            #pragma unroll
            for (int nt = 0; nt < 2; nt++)
                acc[mt * 2 + nt] = __builtin_amdgcn_mfma_f32_16x16x32_f16(Af[mt * 16 + ks].h, bF[nt], acc[mt * 2 + nt], 0, 0, 0);
    }

    // scatter-store fp16 results into frag layout
    #pragma unroll
    for (int mt = 0; mt < 2; mt++)
        #pragma unroll
        for (int nt = 0; nt < 2; nt++)
            #pragma unroll
            for (int r = 0; r < 4; r++) {
                int j  = j0 + nt * 16 + ln;
                int k2 = khalf * 128 + w * 32 + mt * 16 + quad * 4 + r;
                hF[fragIdx(j, k2)] = (_Float16)acc[mt * 2 + nt][r];
            }
}

// ---------- score: C[k2][j] = W2^T h1^T, fused relu/b2/W3 epilogue ----------
// grid 1568 = (jsb 0..48) x (i 0..31); 256 thr = 4 waves (k2-slice 64); 2 tiles of 64 j
__global__ __launch_bounds__(256, 2) void score_kernel(const _Float16* __restrict__ hF,
                                                       const _Float16* __restrict__ g16,
                                                       const _Float16* __restrict__ W2F,
                                                       const float* __restrict__ b2,
                                                       const float* __restrict__ W3,
                                                       const float* __restrict__ b3,
                                                       float* __restrict__ scores) {
    __shared__ float sRed[2][64][4];
    int tid = threadIdx.x, w = tid >> 6, l = tid & 63, quad = l >> 4, ln = l & 15;
    int bid = blockIdx.x;
    int i = bid & 31, jsb = bid >> 5;

    // W2 A-frags, resident all kernel: k2-slice = w*64..w*64+63
    F4H8 Af[32];
    {
        const f4* src = (const f4*)W2F + l;
        #pragma unroll
        for (int mt = 0; mt < 4; mt++)
            #pragma unroll
            for (int ks = 0; ks < 8; ks++)
                Af[mt * 8 + ks].f = src[(size_t)((w * 4 + mt) * 8 + ks) * 64];
    }
    float b2q[16], w3q[16];
    #pragma unroll
    for (int mt = 0; mt < 4; mt++)
        #pragma unroll
        for (int r = 0; r < 4; r++) {
            int k2 = w * 64 + mt * 16 + quad * 4 + r;
            b2q[mt * 4 + r] = b2[k2];
            w3q[mt * 4 + r] = W3[k2];
        }
    float bias3 = b3[0];
    const _Float16* gbase = g16 + i * HID + quad * 8;   // + ks*32

    #pragma unroll 1
    for (int t = 0; t < 2; t++) {
        int jt = jsb * 2 + t;                 // 0..97
        int j0 = jt * 64;
        const _Float16* hbase = hF + (size_t)jt * 16384 + l * 8;

        f4 acc[16];
        #pragma unroll
        for (int mt = 0; mt < 4; mt++)
            #pragma unroll
            for (int nt = 0; nt < 4; nt++)
                #pragma unroll
                for (int r = 0; r < 4; r++) acc[mt * 4 + nt][r] = b2q[mt * 4 + r];

        #pragma unroll
        for (int ks = 0; ks < 8; ks++) {
            h8 gq = *(const h8*)(gbase + ks * 32);
            h8 z = {};
            #pragma unroll
            for (int nt = 0; nt < 4; nt++) {
                h8 hv = *(const h8*)(hbase + (ks * 4 + nt) * 512);
                h8 hz = __builtin_elementwise_max(hv + gq, z);
                #pragma unroll
                for (int mt = 0; mt < 4; mt++)
                    acc[mt * 4 + nt] = __builtin_amdgcn_mfma_f32_16x16x32_f16(Af[mt * 8 + ks].h, hz, acc[mt * 4 + nt], 0, 0, 0);
            }
        }

        // epilogue: relu(h2) . W3 — reduce over k2 (m axis): in-lane + 2 shuffles + LDS
        #pragma unroll
        for (int nt = 0; nt < 4; nt++) {
            float s = 0.f;
            #pragma unroll
            for (int mt = 0; mt < 4; mt++)
                #pragma unroll
                for (int r = 0; r < 4; r++)
                    s += fmaxf(acc[mt * 4 + nt][r], 0.f) * w3q[mt * 4 + r];
            s += __shfl_xor(s, 16, 64);
            s += __shfl_xor(s, 32, 64);
            if (quad == 0) sRed[t & 1][nt * 16 + ln][w] = s;
        }
        __syncthreads();
        if (tid < 64) {
            f4 v = *(const f4*)&sRed[t & 1][tid][0];
            scores[(size_t)i * NHW + j0 + tid] = v.x + v.y + v.z + v.w + bias3;
        }
    }
}

// ---------- reduce: per-row max, masked log-mean-exp, write mi ----------
__global__ __launch_bounds__(256) void reduce_kernel(const float* __restrict__ scores,
                                                     float* __restrict__ out) {
    int i = blockIdx.x, tid = threadIdx.x;
    const float* row = scores + (size_t)i * NHW;
    __shared__ float sA_[4], sB_[4], sval[2];
    float mx = -1e30f;
    for (int j = tid; j < NHW; j += 256) mx = fmaxf(mx, row[j]);
    #pragma unroll
    for (int off = 32; off > 0; off >>= 1) mx = fmaxf(mx, __shfl_down(mx, off, 64));
    if ((tid & 63) == 0) sA_[tid >> 6] = mx;
    __syncthreads();
    if (tid == 0) sval[0] = fmaxf(fmaxf(sA_[0], sA_[1]), fmaxf(sA_[2], sA_[3]));
    __syncthreads();
    mx = sval[0];
    int own0 = i * HWP, own1 = own0 + HWP;
    float tot = 0.f, ownv = 0.f;
    for (int j = tid; j < NHW; j += 256) {
        float e = expf(row[j] - mx);
        tot += e;
        if (j >= own0 && j < own1) ownv += e;
    }
    #pragma unroll
    for (int off = 32; off > 0; off >>= 1) {
        tot  += __shfl_down(tot, off, 64);
        ownv += __shfl_down(ownv, off, 64);
    }
    if ((tid & 63) == 0) { sA_[tid >> 6] = tot; sB_[tid >> 6] = ownv; }
    __syncthreads();
    if (tid == 0) {
        float tv = sA_[0] + sA_[1] + sA_[2] + sA_[3];
        float ov = sB_[0] + sB_[1] + sB_[2] + sB_[3];
        float neg_mean = (tv - ov) / (float)(NHW - HWP) + 1e-10f;
        sval[1] = mx + logf(neg_mean);
    }
    __syncthreads();
    float sub = sval[1];
    if (tid < HWP) out[(size_t)i * HWP + tid] = row[own0 + tid] - sub;
}

extern "C" void kernel_launch(void* const* d_in, const int* in_sizes, int n_in,
                              void* d_out, int out_size, void* d_ws, size_t ws_size,
                              hipStream_t stream) {
    const float* lf = (const float*)d_in[0];
    const float* gf = (const float*)d_in[1];
    const float* W1 = (const float*)d_in[2];
    const float* b1 = (const float*)d_in[3];
    const float* W2 = (const float*)d_in[4];
    const float* b2 = (const float*)d_in[5];
    const float* W3 = (const float*)d_in[6];
    const float* b3 = (const float*)d_in[7];
    float* out = (float*)d_out;

    char* ws = (char*)d_ws;
    _Float16* hF     = (_Float16*)ws;                                  // 6272*256*2 = 3.21 MB
    _Float16* g16    = (_Float16*)(ws + 3211264);                      // 16 KB
    _Float16* W2F    = (_Float16*)(ws + 3227648);                      // 128 KB
    _Float16* W1F    = (_Float16*)(ws + 3358720);                      // 256 KB
    float*    scores = (float*)   (ws + 3620864);                      // 802.8 KB
    float*    hpart  = (float*)   (ws + 4423680);                      // 512 KB spare region

    hipLaunchKernelGGL(hglb1_kernel, dim3(NB, 16), dim3(256), 0, stream, gf, W1, hpart);
    hipLaunchKernelGGL(hglb2_kernel, dim3(NB), dim3(256), 0, stream, hpart, b1, g16);
    hipLaunchKernelGGL(w2frag_kernel, dim3(32), dim3(256), 0, stream, W2, W2F);
    hipLaunchKernelGGL(w1frag_kernel, dim3(64), dim3(256), 0, stream, W1 + (size_t)DD * HID, W1F);
    hipLaunchKernelGGL(hlocF_kernel, dim3(196, 2), dim3(256), 0, stream, lf, W1F, hF);
    hipLaunchKernelGGL(score_kernel, dim3(1568), dim3(256), 0, stream,
                       hF, g16, W2F, b2, W3, b3, scores);
    hipLaunchKernelGGL(reduce_kernel, dim3(NB), dim3(256), 0, stream, scores, out);
}

// Round 4
// 145.211 us; speedup vs baseline: 4.5873x; 1.4278x over previous
//
#include <hip/hip_runtime.h>
#include <math.h>

#define NB   32
#define CC   512
#define DD   2048
#define HWP  196
#define NHW  6272
#define HID  256

typedef _Float16 h8 __attribute__((ext_vector_type(8)));
typedef _Float16 h4 __attribute__((ext_vector_type(4)));
typedef float    f4 __attribute__((ext_vector_type(4)));
union F4H8 { f4 f; h8 h; };

// fp16 index into fragment-layout tensor for (row j, col k), K=256, 64-row j-tiles.
__device__ __forceinline__ int fragIdx(int j, int k) {
    return ((j >> 6) << 14) + (((k >> 5) * 4 + ((j & 63) >> 4)) << 9)
         + (((((k >> 3) & 3) << 4) + (j & 15)) << 3) + (k & 7);
}

// ================= prep: hglb + W2/W1 frags + lf transpose, one dispatch =================
// bid 0..31: g16[i] = fp16(gf[i] @ W1[:2048] + b1)
// bid 32..55: W2F / W1F fragment packing
// bid 56..119: lf16T[j][c] = fp16(lf[n][c][p]),  j = n*196+p
__global__ __launch_bounds__(1024) void prep_kernel(const float* __restrict__ lf,
                                                    const float* __restrict__ gf,
                                                    const float* __restrict__ W1,
                                                    const float* __restrict__ b1,
                                                    const float* __restrict__ W2,
                                                    _Float16* __restrict__ g16,
                                                    _Float16* __restrict__ W2F,
                                                    _Float16* __restrict__ W1F,
                                                    _Float16* __restrict__ lf16T) {
    int bid = blockIdx.x, tid = threadIdx.x;
    if (bid < 32) {
        __shared__ float sP[4][HID];
        int i = bid, k = tid & 255, rc = tid >> 8;
        const float* g = gf + (size_t)i * DD;
        int r0 = rc * 512;
        float acc = 0.f;
        #pragma unroll 8
        for (int r = 0; r < 512; r++)
            acc = fmaf(g[r0 + r], W1[(size_t)(r0 + r) * HID + k], acc);
        sP[rc][k] = acc;
        __syncthreads();
        if (tid < HID)
            g16[(size_t)i * HID + tid] =
                (_Float16)(b1[tid] + sP[0][tid] + sP[1][tid] + sP[2][tid] + sP[3][tid]);
    } else if (bid < 56) {
        int tg = (bid - 32) * 1024 + tid;            // 0..24575
        if (tg < 8192) {
            int t = tg, F = t >> 6, l = t & 63;
            int k2t = F >> 3, ks = F & 7;
            int kb = ks * 32 + (l >> 4) * 8;
            int n  = k2t * 16 + (l & 15);
            _Float16* o = W2F + (size_t)t * 8;
            #pragma unroll
            for (int j = 0; j < 8; j++) o[j] = (_Float16)W2[(size_t)(kb + j) * HID + n];
        } else {
            int t = tg - 8192, F = t >> 6, l = t & 63;
            int k2t = F >> 4, ks = F & 15;
            int kb = ks * 32 + (l >> 4) * 8;
            int n  = k2t * 16 + (l & 15);
            const float* W1c = W1 + (size_t)DD * HID;
            _Float16* o = W1F + (size_t)t * 8;
            #pragma unroll
            for (int j = 0; j < 8; j++) o[j] = (_Float16)W1c[(size_t)(kb + j) * HID + n];
        }
    } else {
        __shared__ _Float16 sT[64][HWP + 4];         // 200 fp16 rows: 8B-aligned, odd dword stride
        int b = bid - 56;
        int n = b >> 1, half = b & 1;
        for (int cb = 0; cb < 4; cb++) {
            int c0 = half * 256 + cb * 64;
            for (int task = tid; task < 64 * 49; task += 1024) {
                int c = task / 49, f = task - c * 49;
                f4 v = *(const f4*)&lf[((size_t)n * CC + c0 + c) * HWP + f * 4];
                h4 o = { (_Float16)v.x, (_Float16)v.y, (_Float16)v.z, (_Float16)v.w };
                *(h4*)&sT[c][f * 4] = o;
            }
            __syncthreads();
            for (int task = tid; task < HWP * 8; task += 1024) {
                int p = task >> 3, ch = task & 7;
                h8 o;
                #pragma unroll
                for (int cc = 0; cc < 8; cc++) o[cc] = sT[ch * 8 + cc][p];
                *(h8*)&lf16T[((size_t)(n * HWP + p)) * CC + c0 + ch * 8] = o;
            }
            __syncthreads();
        }
    }
}

// ================= hlocF: h_loc = lf16T @ W1[D:], MFMA, frag-layout output =================
// grid (196 j-tiles of 32, 2 k2-halves), 256 thr = 4 waves (k2-slice 32 each)
__global__ __launch_bounds__(256, 2) void hlocF_kernel(const _Float16* __restrict__ lf16T,
                                                       const _Float16* __restrict__ W1F,
                                                       _Float16* __restrict__ hF) {
    __shared__ _Float16 sLf[32][CC + 16];
    int tid = threadIdx.x;
    int w = tid >> 6, l = tid & 63, quad = l >> 4, ln = l & 15;
    int j0 = blockIdx.x * 32;
    int khalf = blockIdx.y;

    // stage 32x512 fp16 tile, coalesced h8 loads
    #pragma unroll
    for (int s = 0; s < 8; s++) {
        int y = s * 256 + tid;
        int row = y >> 6, col = (y & 63) * 8;
        h8 v = *(const h8*)&lf16T[(size_t)(j0 + row) * CC + col];
        *(h8*)&sLf[row][col] = v;
    }

    // W1 A-frags for this wave's 32-wide k2-slice
    F4H8 Af[32];
    {
        const f4* src = (const f4*)W1F + l;
        #pragma unroll
        for (int mt = 0; mt < 2; mt++)
            #pragma unroll
            for (int ks = 0; ks < 16; ks++)
                Af[mt * 16 + ks].f = src[(size_t)((khalf * 8 + w * 2 + mt) * 16 + ks) * 64];
    }
    __syncthreads();

    f4 acc[4] = {};
    #pragma unroll
    for (int ks = 0; ks < 16; ks++) {
        h8 bF[2];
        #pragma unroll
        for (int nt = 0; nt < 2; nt++)
            bF[nt] = *(const h8*)&sLf[nt * 16 + ln][ks * 32 + quad * 8];
        #pragma unroll
        for (int mt = 0; mt < 2; mt++)
            #pragma unroll
            for (int nt = 0; nt < 2; nt++)
                acc[mt * 2 + nt] = __builtin_amdgcn_mfma_f32_16x16x32_f16(Af[mt * 16 + ks].h, bF[nt], acc[mt * 2 + nt], 0, 0, 0);
    }

    #pragma unroll
    for (int mt = 0; mt < 2; mt++)
        #pragma unroll
        for (int nt = 0; nt < 2; nt++)
            #pragma unroll
            for (int r = 0; r < 4; r++) {
                int j  = j0 + nt * 16 + ln;
                int k2 = khalf * 128 + w * 32 + mt * 16 + quad * 4 + r;
                hF[fragIdx(j, k2)] = (_Float16)acc[mt * 2 + nt][r];
            }
}

// ================= score: C[k2][j] = W2^T h1^T + fused epilogue =================
// grid 3136 = (jt 0..97) x (i 0..31); 256 thr = 4 waves (k2-slice 64); h1 tile in LDS
__global__ __launch_bounds__(256, 2) void score_kernel(const _Float16* __restrict__ hF,
                                                       const _Float16* __restrict__ g16,
                                                       const _Float16* __restrict__ W2F,
                                                       const float* __restrict__ b2,
                                                       const float* __restrict__ W3,
                                                       const float* __restrict__ b3,
                                                       float* __restrict__ scores) {
    __shared__ _Float16 sA[64 * HID];     // 32 KB, frag layout (same as hF tile)
    __shared__ float sRed[64][4];
    int tid = threadIdx.x, w = tid >> 6, l = tid & 63, quad = l >> 4, ln = l & 15;
    int bid = blockIdx.x;
    int i = bid & 31, jt = bid >> 5;      // 0..97

    // W2 A-frags, resident: k2-slice w*64..w*64+63
    F4H8 Af[32];
    {
        const f4* src = (const f4*)W2F + l;
        #pragma unroll
        for (int mt = 0; mt < 4; mt++)
            #pragma unroll
            for (int ks = 0; ks < 8; ks++)
                Af[mt * 8 + ks].f = src[(size_t)((w * 4 + mt) * 8 + ks) * 64];
    }

    // stage: h1 = relu(hF + g) -> LDS, g-add applied once per block
    {
        const _Float16* hbase = hF + (size_t)jt * 16384;
        const _Float16* gbase = g16 + (size_t)i * HID;
        h8 z = {};
        #pragma unroll
        for (int s = 0; s < 8; s++) {
            int y = s * 256 + tid;
            h8 hv = *(const h8*)&hbase[y * 8];
            h8 gq = *(const h8*)&gbase[s * 32 + ((tid >> 4) & 3) * 8];
            h8 hz = __builtin_elementwise_max(hv + gq, z);
            *(h8*)&sA[y * 8] = hz;
        }
    }
    __syncthreads();

    // acc init = b2 (transient f4 loads, not resident)
    f4 acc[16];
    #pragma unroll
    for (int mt = 0; mt < 4; mt++) {
        f4 bv = *(const f4*)&b2[w * 64 + mt * 16 + quad * 4];
        #pragma unroll
        for (int nt = 0; nt < 4; nt++) acc[mt * 4 + nt] = bv;
    }

    // K-loop: pure ds_read_b128 + MFMA
    #pragma unroll
    for (int ks = 0; ks < 8; ks++) {
        #pragma unroll
        for (int nt = 0; nt < 4; nt++) {
            h8 hz = *(const h8*)&sA[(ks * 4 + nt) * 512 + l * 8];
            #pragma unroll
            for (int mt = 0; mt < 4; mt++)
                acc[mt * 4 + nt] = __builtin_amdgcn_mfma_f32_16x16x32_f16(Af[mt * 8 + ks].h, hz, acc[mt * 4 + nt], 0, 0, 0);
        }
    }

    // epilogue: relu . W3 (transient f4 loads), reduce over k2
    #pragma unroll
    for (int nt = 0; nt < 4; nt++) {
        float s = 0.f;
        #pragma unroll
        for (int mt = 0; mt < 4; mt++) {
            f4 w3v = *(const f4*)&W3[w * 64 + mt * 16 + quad * 4];
            s += fmaxf(acc[mt * 4 + nt][0], 0.f) * w3v.x
               + fmaxf(acc[mt * 4 + nt][1], 0.f) * w3v.y
               + fmaxf(acc[mt * 4 + nt][2], 0.f) * w3v.z
               + fmaxf(acc[mt * 4 + nt][3], 0.f) * w3v.w;
        }
        s += __shfl_xor(s, 16, 64);
        s += __shfl_xor(s, 32, 64);
        if (quad == 0) sRed[nt * 16 + ln][w] = s;
    }
    __syncthreads();
    if (tid < 64) {
        f4 v = *(const f4*)&sRed[tid][0];
        scores[(size_t)i * NHW + jt * 64 + tid] = v.x + v.y + v.z + v.w + b3[0];
    }
}

// ================= reduce: per-row max, masked log-mean-exp =================
__global__ __launch_bounds__(1024) void reduce_kernel(const float* __restrict__ scores,
                                                      float* __restrict__ out) {
    int i = blockIdx.x, tid = threadIdx.x;
    const float* row = scores + (size_t)i * NHW;
    const f4* row4 = (const f4*)row;                 // 1568 f4
    __shared__ float sW[16], sW2[16], sval[2];
    float mx = -1e30f;
    for (int q = tid; q < 1568; q += 1024) {
        f4 v = row4[q];
        mx = fmaxf(mx, fmaxf(fmaxf(v.x, v.y), fmaxf(v.z, v.w)));
    }
    #pragma unroll
    for (int off = 32; off > 0; off >>= 1) mx = fmaxf(mx, __shfl_down(mx, off, 64));
    if ((tid & 63) == 0) sW[tid >> 6] = mx;
    __syncthreads();
    if (tid == 0) {
        float m = sW[0];
        for (int c = 1; c < 16; c++) m = fmaxf(m, sW[c]);
        sval[0] = m;
    }
    __syncthreads();
    mx = sval[0];
    int q0 = i * 49, q1 = q0 + 49;                   // own f4-range (196 = 49*4, i*196 % 4 == 0)
    float tot = 0.f, ownv = 0.f;
    for (int q = tid; q < 1568; q += 1024) {
        f4 v = row4[q];
        float e = expf(v.x - mx) + expf(v.y - mx) + expf(v.z - mx) + expf(v.w - mx);
        tot += e;
        if (q >= q0 && q < q1) ownv += e;
    }
    #pragma unroll
    for (int off = 32; off > 0; off >>= 1) {
        tot  += __shfl_down(tot, off, 64);
        ownv += __shfl_down(ownv, off, 64);
    }
    if ((tid & 63) == 0) { sW[tid >> 6] = tot; sW2[tid >> 6] = ownv; }
    __syncthreads();
    if (tid == 0) {
        float t = 0.f, o = 0.f;
        for (int c = 0; c < 16; c++) { t += sW[c]; o += sW2[c]; }
        float neg_mean = (t - o) / (float)(NHW - HWP) + 1e-10f;
        sval[1] = mx + logf(neg_mean);
    }
    __syncthreads();
    float sub = sval[1];
    if (tid < HWP) out[(size_t)i * HWP + tid] = row[i * HWP + tid] - sub;
}

extern "C" void kernel_launch(void* const* d_in, const int* in_sizes, int n_in,
                              void* d_out, int out_size, void* d_ws, size_t ws_size,
                              hipStream_t stream) {
    const float* lf = (const float*)d_in[0];
    const float* gf = (const float*)d_in[1];
    const float* W1 = (const float*)d_in[2];
    const float* b1 = (const float*)d_in[3];
    const float* W2 = (const float*)d_in[4];
    const float* b2 = (const float*)d_in[5];
    const float* W3 = (const float*)d_in[6];
    const float* b3 = (const float*)d_in[7];
    float* out = (float*)d_out;

    char* ws = (char*)d_ws;
    _Float16* hF     = (_Float16*)ws;                      // 3,211,264 B
    _Float16* g16    = (_Float16*)(ws + 3211264);          // 16 KB
    _Float16* W2F    = (_Float16*)(ws + 3227648);          // 128 KB
    _Float16* W1F    = (_Float16*)(ws + 3358720);          // 256 KB
    _Float16* lf16T  = (_Float16*)(ws + 3620864);          // 6,422,528 B
    float*    scores = (float*)   (ws + 10043392);         // 802,816 B

    hipLaunchKernelGGL(prep_kernel, dim3(120), dim3(1024), 0, stream,
                       lf, gf, W1, b1, W2, g16, W2F, W1F, lf16T);
    hipLaunchKernelGGL(hlocF_kernel, dim3(196, 2), dim3(256), 0, stream, lf16T, W1F, hF);
    hipLaunchKernelGGL(score_kernel, dim3(3136), dim3(256), 0, stream,
                       hF, g16, W2F, b2, W3, b3, scores);
    hipLaunchKernelGGL(reduce_kernel, dim3(NB), dim3(1024), 0, stream, scores, out);
}